// Round 8
// baseline (870.590 us; speedup 1.0000x reference)
//
#include <hip/hip_runtime.h>
#include <stdint.h>

#define EPS 1e-5f

typedef __attribute__((ext_vector_type(8))) __bf16 bf16x8;
typedef __attribute__((ext_vector_type(16))) float f32x16;

__device__ __forceinline__ int swz4(int r) { return (r ^ (r >> 2)) & 3; }

__device__ __forceinline__ unsigned short f2bf(float f) {
  union { float f; unsigned u; } v; v.f = f;
  unsigned r = v.u + 0x7fffu + ((v.u >> 16) & 1u);
  return (unsigned short)(r >> 16);
}

__device__ __forceinline__ void glds16(const unsigned short* g, unsigned short* l) {
  __builtin_amdgcn_global_load_lds(
      (const __attribute__((address_space(1))) void*)g,
      (__attribute__((address_space(3))) void*)l, 16, 0, 0);
}
__device__ __forceinline__ void glds4(const unsigned short* g, unsigned short* l) {
  __builtin_amdgcn_global_load_lds(
      (const __attribute__((address_space(1))) void*)g,
      (__attribute__((address_space(3))) void*)l, 4, 0, 0);
}

template <int N>
__device__ __forceinline__ void vmwait() {
  asm volatile("s_waitcnt vmcnt(%0)" ::"n"(N) : "memory");
}

// ---------------------------------------------------------------------------
// Pack W [c2][c1][13][13] f32 -> bf16 per-K-step tiles laid out for COALESCED
// direct global->VGPR fragment loads:
// tile(4096 ush): [ks 2][mglob 4][hi2 2][l31 32][j 8]
//   where k = (ks*2+hi2)*8 + j, m = mglob*32 + l31.
// K order: k-step = (kh*8 + c1c)*13 + kw
// ---------------------------------------------------------------------------
__global__ __launch_bounds__(256) void pack_w_kernel(
    const float* __restrict__ W, unsigned short* __restrict__ Wp) {
  const int blk = blockIdx.x;  // c2*13 + kh
  const int c2 = blk / 13, kh = blk - c2 * 13;
  const int c1 = threadIdx.x;
  const int c2t = c2 >> 7, m = c2 & 127;
  const int c1c = c1 >> 5, c1i = c1 & 31;
  const float* src = W + (((size_t)(c2 * 256 + c1)) * 13 + kh) * 13;
  const int chunk = c1i >> 3, j = c1i & 7;
  const int intile = (chunk >> 1) * 2048 + (m >> 5) * 512 + (chunk & 1) * 256 +
                     (m & 31) * 8 + j;
#pragma unroll
  for (int kw = 0; kw < 13; ++kw) {
    const int ks = (kh * 8 + c1c) * 13 + kw;
    Wp[((size_t)c2t * 1352 + ks) * 4096 + intile] = f2bf(src[kw]);
  }
}

// ---------------------------------------------------------------------------
// Pack x [b][c1][64][64] f32 -> xT[b][c1c][rowp 76][colp 80][c1i 32] bf16,
// zero-padded halo (rowp = row+6, colp = ic+8), chunk swizzle baked in.
// ---------------------------------------------------------------------------
__global__ __launch_bounds__(256) void pack_xt_kernel(
    const float* __restrict__ x, unsigned short* __restrict__ xT) {
  const int blk = blockIdx.x;  // (b*8 + c1c)*76 + rowp ; 4864 blocks
  const int rowp = blk % 76;
  const int bc = blk / 76;
  const int c1c = bc & 7, b = bc >> 3;
  const int row = rowp - 6;
  const bool rok = (unsigned)row < 64u;
  unsigned short* dst = xT + (size_t)blk * 2560;
  const float* srcb = x + (size_t)(b * 256 + c1c * 32) * 4096 +
                      (rok ? row * 64 : 0);
#pragma unroll
  for (int e = 0; e < 10; ++e) {
    const int idx = e * 256 + threadIdx.x;  // 0..2559
    const int colp = idx >> 5, c1i = idx & 31;
    const int ic = colp - 8;
    const float v = (rok && (unsigned)ic < 64u) ? srcb[(size_t)c1i * 4096 + ic] : 0.f;
    dst[colp * 32 + ((((c1i >> 3) ^ swz4(colp)) << 3)) + (c1i & 7)] = f2bf(v);
  }
}

// ---------------------------------------------------------------------------
// Implicit-GEMM conv + BN + SiLU.
// Block: 256 thr (4 waves 2M x 2N), tile 128 c2 x 128 sp (2h x 64w).
// A: direct global->VGPR, DEPTH-2 prefetch via 3-buffer rotation (39-phase
// static schedule, 39 % 3 == 0). B: window in LDS (swizzled), read in-phase.
// One barrier/phase, uniform vmwait<8>. Grid 512 -> 2 blocks/CU.
// ---------------------------------------------------------------------------
__global__ __launch_bounds__(256, 2) void conv8_kernel(
    const unsigned short* __restrict__ Wp, const unsigned short* __restrict__ xT,
    const float* __restrict__ gamma, const float* __restrict__ beta,
    const float* __restrict__ mean, const float* __restrict__ var,
    float* __restrict__ out) {
  __shared__ __align__(16) unsigned short Wbuf[2][5120];  // 2 x 10 KiB
  __shared__ float s_scale[128], s_shift[128];

  const int tid = threadIdx.x;
  const int bid = blockIdx.x;
  const int b = bid & 7;  // XCD-aware: blocks on XCD k share batch image k
  const int h0 = ((bid >> 3) & 31) * 2;
  const int c2t = bid >> 8;

  const int wid = tid >> 6, lane = tid & 63;
  const int wr = wid >> 1, wc = wid & 1;
  const int l31 = lane & 31, hi2 = lane >> 5;

  if (tid < 128) {
    const int c2 = c2t * 128 + tid;
    const float inv = gamma[c2] * rsqrtf(var[c2] + EPS);
    s_scale[tid] = inv;
    s_shift[tid] = beta[c2] - mean[c2] * inv;
  }

  // A direct-load byte offsets within an 8192-byte tile (coalesced layout)
  int offA[2][2];
#pragma unroll
  for (int ks = 0; ks < 2; ++ks)
#pragma unroll
    for (int mt = 0; mt < 2; ++mt)
      offA[ks][mt] = ks * 4096 + (wr * 2 + mt) * 1024 + hi2 * 512 + l31 * 16;
  int ndh[2], nwl[2];
#pragma unroll
  for (int nt = 0; nt < 2; ++nt) {
    const int n = wc * 64 + nt * 32 + l31;
    ndh[nt] = n >> 6;
    nwl[nt] = n & 63;
  }

  const int tid8 = tid * 8, tid2 = tid * 2;
  const int widA = wid * 512, wid128 = wid * 128;

  const size_t c2base = (size_t)c2t * 1352;
  const int bc8 = b * 8;
  const char* WpB = (const char*)Wp;

  auto wtile = [&](int T) -> const unsigned short* {
    const int kh = T >> 3, c1c = T & 7;
    return xT + (size_t)((bc8 + c1c) * 76 + h0 + kh) * 2560;
  };

  f32x16 acc[2][2];
#pragma unroll
  for (int i = 0; i < 2; ++i)
#pragma unroll
    for (int j = 0; j < 2; ++j)
#pragma unroll
      for (int r = 0; r < 16; ++r) acc[i][j][r] = 0.f;

  // A fragment registers: 3-buffer rotation [step][ks][mt]; B single buffer
  bf16x8 aR0[2][2][2], aR1[2][2][2], aR2[2][2][2], bR[2][2][2];

#define LOADA(DST, SN0E, SN1E)                                                \
  {                                                                           \
    int sn0 = (SN0E);                                                         \
    if (sn0 >= 1352) sn0 -= 1352;                                             \
    int sn1 = (SN1E);                                                         \
    if (sn1 >= 1352) sn1 -= 1352;                                             \
    const char* at0 = WpB + ((c2base + (size_t)sn0) << 13);                   \
    const char* at1 = WpB + ((c2base + (size_t)sn1) << 13);                   \
    _Pragma("unroll") for (int ks = 0; ks < 2; ++ks)                          \
        _Pragma("unroll") for (int mt = 0; mt < 2; ++mt) {                    \
      DST[0][ks][mt] = *(const bf16x8*)(at0 + offA[ks][mt]);                  \
      DST[1][ks][mt] = *(const bf16x8*)(at1 + offA[ks][mt]);                  \
    }                                                                         \
  }

  // ---- prologue: stage window tile0; preload aR0 (steps 0,1), aR1 (2,3)
  {
    const unsigned short* ws = wtile(0);
    glds16(ws + tid8, &Wbuf[0][0] + widA);
    glds16(ws + 2048 + tid8, &Wbuf[0][2048] + widA);
    glds4(ws + 4096 + tid2, &Wbuf[0][4096] + wid128);
    glds4(ws + 4608 + tid2, &Wbuf[0][4608] + wid128);
    vmwait<0>();
    __builtin_amdgcn_s_barrier();
    LOADA(aR0, 0, 1)
    LOADA(aR1, 2, 3)
    vmwait<8>();  // aR0 complete; aR1 in flight (steady-state invariant)
  }

// one phase: W glds round -> A issue (p+2) -> B ds reads (this phase)
// -> pure-reg MFMA -> vmwait<8> -> barrier.
#define PHASE(J, AC, AN, KWA, WBA, KWB, WBB, WRT, WSRCP, WDB)                 \
  {                                                                           \
    if ((WRT) == 1) glds16((WSRCP) + tid8, &Wbuf[(WDB)][0] + widA);           \
    if ((WRT) == 2)                                                           \
      glds16((WSRCP) + 2048 + tid8, &Wbuf[(WDB)][2048] + widA);               \
    if ((WRT) == 3) {                                                         \
      glds4((WSRCP) + 4096 + tid2, &Wbuf[(WDB)][4096] + wid128);              \
      glds4((WSRCP) + 4608 + tid2, &Wbuf[(WDB)][4608] + wid128);              \
    }                                                                         \
    LOADA(AN, S0 + 2 * (J) + 4, S0 + 2 * (J) + 5)                             \
    {                                                                         \
      const char* wbA = (const char*)&Wbuf[(WBA)][0];                         \
      const char* wbB = (const char*)&Wbuf[(WBB)][0];                         \
      _Pragma("unroll") for (int ks = 0; ks < 2; ++ks)                        \
          _Pragma("unroll") for (int nt = 0; nt < 2; ++nt) {                  \
        const int cA = nwl[nt] + (KWA) + 2;                                   \
        bR[0][ks][nt] = *(const bf16x8*)(                                     \
            wbA + (ndh[nt] * 80 + cA) * 64 +                                  \
            (((ks * 2 + hi2) ^ swz4(cA)) << 4));                              \
        const int cB = nwl[nt] + (KWB) + 2;                                   \
        bR[1][ks][nt] = *(const bf16x8*)(                                     \
            wbB + (ndh[nt] * 80 + cB) * 64 +                                  \
            (((ks * 2 + hi2) ^ swz4(cB)) << 4));                              \
      }                                                                       \
    }                                                                         \
    {                                                                         \
      __builtin_amdgcn_s_setprio(1);                                          \
      _Pragma("unroll") for (int s = 0; s < 2; ++s)                           \
          _Pragma("unroll") for (int ks = 0; ks < 2; ++ks) {                  \
        acc[0][0] = __builtin_amdgcn_mfma_f32_32x32x16_bf16(                  \
            AC[s][ks][0], bR[s][ks][0], acc[0][0], 0, 0, 0);                  \
        acc[0][1] = __builtin_amdgcn_mfma_f32_32x32x16_bf16(                  \
            AC[s][ks][0], bR[s][ks][1], acc[0][1], 0, 0, 0);                  \
        acc[1][0] = __builtin_amdgcn_mfma_f32_32x32x16_bf16(                  \
            AC[s][ks][1], bR[s][ks][0], acc[1][0], 0, 0, 0);                  \
        acc[1][1] = __builtin_amdgcn_mfma_f32_32x32x16_bf16(                  \
            AC[s][ks][1], bR[s][ks][1], acc[1][1], 0, 0, 0);                  \
      }                                                                       \
      __builtin_amdgcn_s_setprio(0);                                          \
    }                                                                         \
    vmwait<8>(); /* drain all but this phase's 8 A loads */                   \
    __builtin_amdgcn_s_barrier();                                             \
    __builtin_amdgcn_sched_barrier(0);                                        \
  }

  // ---- main: 17 u-iterations x 6 tiles (39 phases each; 39 % 3 == 0)
  for (int u = 0; u < 17; ++u) {
    const int S0 = u * 78;
    const int Tb = u * 6;
    const unsigned short* wt1 = wtile(Tb + 1);
    const unsigned short* wt2 = wtile(Tb + 2);
    const unsigned short* wt3 = wtile(Tb + 3);
    const unsigned short* wt4 = wtile(Tb + 4);
    const unsigned short* wt5 = wtile(Tb + 5);
    const unsigned short* wt6 = wtile(Tb + 6);
    PHASE(0, aR0, aR2, 0, 0, 1, 0, 0, wt1, 1)
    PHASE(1, aR1, aR0, 2, 0, 3, 0, 1, wt1, 1)
    PHASE(2, aR2, aR1, 4, 0, 5, 0, 2, wt1, 1)
    PHASE(3, aR0, aR2, 6, 0, 7, 0, 3, wt1, 1)
    PHASE(4, aR1, aR0, 8, 0, 9, 0, 0, wt1, 1)
    PHASE(5, aR2, aR1, 10, 0, 11, 0, 0, wt1, 1)
    PHASE(6, aR0, aR2, 12, 0, 0, 1, 0, wt1, 1)
    PHASE(7, aR1, aR0, 1, 1, 2, 1, 0, wt2, 0)
    PHASE(8, aR2, aR1, 3, 1, 4, 1, 1, wt2, 0)
    PHASE(9, aR0, aR2, 5, 1, 6, 1, 2, wt2, 0)
    PHASE(10, aR1, aR0, 7, 1, 8, 1, 3, wt2, 0)
    PHASE(11, aR2, aR1, 9, 1, 10, 1, 0, wt2, 0)
    PHASE(12, aR0, aR2, 11, 1, 12, 1, 0, wt2, 0)
    PHASE(13, aR1, aR0, 0, 0, 1, 0, 0, wt3, 1)
    PHASE(14, aR2, aR1, 2, 0, 3, 0, 1, wt3, 1)
    PHASE(15, aR0, aR2, 4, 0, 5, 0, 2, wt3, 1)
    PHASE(16, aR1, aR0, 6, 0, 7, 0, 3, wt3, 1)
    PHASE(17, aR2, aR1, 8, 0, 9, 0, 0, wt3, 1)
    PHASE(18, aR0, aR2, 10, 0, 11, 0, 0, wt3, 1)
    PHASE(19, aR1, aR0, 12, 0, 0, 1, 0, wt3, 1)
    PHASE(20, aR2, aR1, 1, 1, 2, 1, 0, wt4, 0)
    PHASE(21, aR0, aR2, 3, 1, 4, 1, 1, wt4, 0)
    PHASE(22, aR1, aR0, 5, 1, 6, 1, 2, wt4, 0)
    PHASE(23, aR2, aR1, 7, 1, 8, 1, 3, wt4, 0)
    PHASE(24, aR0, aR2, 9, 1, 10, 1, 0, wt4, 0)
    PHASE(25, aR1, aR0, 11, 1, 12, 1, 0, wt4, 0)
    PHASE(26, aR2, aR1, 0, 0, 1, 0, 0, wt5, 1)
    PHASE(27, aR0, aR2, 2, 0, 3, 0, 1, wt5, 1)
    PHASE(28, aR1, aR0, 4, 0, 5, 0, 2, wt5, 1)
    PHASE(29, aR2, aR1, 6, 0, 7, 0, 3, wt5, 1)
    PHASE(30, aR0, aR2, 8, 0, 9, 0, 0, wt5, 1)
    PHASE(31, aR1, aR0, 10, 0, 11, 0, 0, wt5, 1)
    PHASE(32, aR2, aR1, 12, 0, 0, 1, 0, wt5, 1)
    PHASE(33, aR0, aR2, 1, 1, 2, 1, 0, wt6, 0)
    PHASE(34, aR1, aR0, 3, 1, 4, 1, 1, wt6, 0)
    PHASE(35, aR2, aR1, 5, 1, 6, 1, 2, wt6, 0)
    PHASE(36, aR0, aR2, 7, 1, 8, 1, 3, wt6, 0)
    PHASE(37, aR1, aR0, 9, 1, 10, 1, 0, wt6, 0)
    PHASE(38, aR2, aR1, 11, 1, 12, 1, 0, wt6, 0)
  }

  // ---- tail: tiles 102,103 (13 phases; starts at global phase 663, %3==0)
  {
    const int S0 = 1326;
    const unsigned short* wtT = wtile(103);
    PHASE(0, aR0, aR2, 0, 0, 1, 0, 0, wtT, 1)
    PHASE(1, aR1, aR0, 2, 0, 3, 0, 1, wtT, 1)
    PHASE(2, aR2, aR1, 4, 0, 5, 0, 2, wtT, 1)
    PHASE(3, aR0, aR2, 6, 0, 7, 0, 3, wtT, 1)
    PHASE(4, aR1, aR0, 8, 0, 9, 0, 0, wtT, 1)
    PHASE(5, aR2, aR1, 10, 0, 11, 0, 0, wtT, 1)
    PHASE(6, aR0, aR2, 12, 0, 0, 1, 0, wtT, 1)
    PHASE(7, aR1, aR0, 1, 1, 2, 1, 0, wtT, 1)
    PHASE(8, aR2, aR1, 3, 1, 4, 1, 0, wtT, 1)
    PHASE(9, aR0, aR2, 5, 1, 6, 1, 0, wtT, 1)
    PHASE(10, aR1, aR0, 7, 1, 8, 1, 0, wtT, 1)
    PHASE(11, aR2, aR1, 9, 1, 10, 1, 0, wtT, 1)
    PHASE(12, aR0, aR2, 11, 1, 12, 1, 0, wtT, 1)
  }
#undef PHASE
#undef LOADA

  vmwait<0>();  // drain dangling prefetches

  // ---- epilogue: BN + SiLU.
  // 32x32 C/D layout (m74/m101): col = lane&31, row = (r&3)+8*(r>>2)+4*(lane>>5)
#pragma unroll
  for (int mt = 0; mt < 2; ++mt) {
#pragma unroll
    for (int nt = 0; nt < 2; ++nt) {
      const int n = wc * 64 + nt * 32 + l31;
      const int hh = h0 + (n >> 6), ww = n & 63;
#pragma unroll
      for (int r = 0; r < 16; ++r) {
        const int mloc = (r & 3) + 8 * (r >> 2) + 4 * hi2;
        const int c2l = wr * 64 + mt * 32 + mloc;
        const float y = acc[mt][nt][r] * s_scale[c2l] + s_shift[c2l];
        out[((size_t)(b * 256 + c2t * 128 + c2l)) * 4096 + hh * 64 + ww] =
            y / (1.f + __expf(-y));
      }
    }
  }
}

// ---------------------------------------------------------------------------
// Safety-net fallback if workspace is too small for packed buffers.
// ---------------------------------------------------------------------------
__global__ void naive_conv_kernel(
    const float* __restrict__ x, const float* __restrict__ W,
    const float* __restrict__ gamma, const float* __restrict__ beta,
    const float* __restrict__ mean, const float* __restrict__ var,
    float* __restrict__ out) {
  const int idx = blockIdx.x * 256 + threadIdx.x;
  if (idx >= 8 * 256 * 64 * 64) return;
  const int w = idx & 63, h = (idx >> 6) & 63;
  const int c2 = (idx >> 12) & 255, b = idx >> 20;
  float s = 0.f;
  for (int c1 = 0; c1 < 256; ++c1) {
    const float* xp = x + ((size_t)(b * 256 + c1) * 4096);
    const float* wp = W + ((size_t)(c2 * 256 + c1) * 169);
    for (int kh = 0; kh < 13; ++kh) {
      const int r = h + kh - 6;
      if ((unsigned)r >= 64u) continue;
      for (int kw = 0; kw < 13; ++kw) {
        const int c = w + kw - 6;
        if ((unsigned)c >= 64u) continue;
        s += xp[r * 64 + c] * wp[kh * 13 + kw];
      }
    }
  }
  const float inv = gamma[c2] * rsqrtf(var[c2] + EPS);
  const float y = s * inv + (beta[c2] - mean[c2] * inv);
  out[idx] = y / (1.f + __expf(-y));
}

extern "C" void kernel_launch(void* const* d_in, const int* in_sizes, int n_in,
                              void* d_out, int out_size, void* d_ws, size_t ws_size,
                              hipStream_t stream) {
  const float* x = (const float*)d_in[0];
  const float* W = (const float*)d_in[1];
  const float* gamma = (const float*)d_in[2];
  const float* beta = (const float*)d_in[3];
  const float* mean = (const float*)d_in[4];
  const float* var = (const float*)d_in[5];
  float* out = (float*)d_out;

  const size_t WP_BYTES = (size_t)256 * 43264 * 2;  // 22,151,168
  const size_t XT_BYTES = (size_t)12455424 * 2;     // 24,910,848

  if (ws_size >= WP_BYTES + XT_BYTES) {
    unsigned short* Wp = (unsigned short*)d_ws;
    unsigned short* xT = (unsigned short*)((char*)d_ws + WP_BYTES);
    pack_w_kernel<<<256 * 13, 256, 0, stream>>>(W, Wp);
    pack_xt_kernel<<<8 * 8 * 76, 256, 0, stream>>>(x, xT);
    conv8_kernel<<<512, 256, 0, stream>>>(Wp, xT, gamma, beta, mean, var, out);
  } else {
    naive_conv_kernel<<<(8 * 256 * 64 * 64 + 255) / 256, 256, 0, stream>>>(
        x, W, gamma, beta, mean, var, out);
  }
}

// Round 9
// 688.338 us; speedup vs baseline: 1.2648x; 1.2648x over previous
//
#include <hip/hip_runtime.h>
#include <stdint.h>

#define EPS 1e-5f

typedef __attribute__((ext_vector_type(8))) __bf16 bf16x8;
typedef __attribute__((ext_vector_type(16))) float f32x16;
typedef __attribute__((ext_vector_type(4))) float f32x4;

__device__ __forceinline__ int swz4(int r) { return (r ^ (r >> 2)) & 3; }

__device__ __forceinline__ unsigned short f2bf(float f) {
  union { float f; unsigned u; } v; v.f = f;
  unsigned r = v.u + 0x7fffu + ((v.u >> 16) & 1u);
  return (unsigned short)(r >> 16);
}

__device__ __forceinline__ void glds16(const unsigned short* g, unsigned short* l) {
  __builtin_amdgcn_global_load_lds(
      (const __attribute__((address_space(1))) void*)g,
      (__attribute__((address_space(3))) void*)l, 16, 0, 0);
}

template <int N>
__device__ __forceinline__ void vmwait() {
  asm volatile("s_waitcnt vmcnt(%0)" ::"n"(N) : "memory");
}

// ---------------------------------------------------------------------------
// Pack W [c2][c1][13][13] f32 -> bf16 per-K-step tiles = exact linear LDS
// image of the A tile (chunk swizzle baked in).  (R6-validated layout)
// K order: k-step = (kh*8 + c1c)*13 + kw ; tile [m 128][slot 4][j 8],
// slot = (c1i>>3) ^ swz4(m)
// ---------------------------------------------------------------------------
__global__ __launch_bounds__(256) void pack_w_kernel(
    const float* __restrict__ W, unsigned short* __restrict__ Wp) {
  const int blk = blockIdx.x;  // c2*13 + kh
  const int c2 = blk / 13, kh = blk - c2 * 13;
  const int c1 = threadIdx.x;
  const int c2t = c2 >> 7, m = c2 & 127;
  const int c1c = c1 >> 5, c1i = c1 & 31;
  const float* src = W + (((size_t)(c2 * 256 + c1)) * 13 + kh) * 13;
  const int rowoff = (((c1i >> 3) ^ swz4(m)) << 3) + (c1i & 7);
#pragma unroll
  for (int kw = 0; kw < 13; ++kw) {
    const int ks = (kh * 8 + c1c) * 13 + kw;
    const size_t dst = (((size_t)c2t * 1352 + ks) * 128 + m) * 32 + rowoff;
    Wp[dst] = f2bf(src[kw]);
  }
}

// ---------------------------------------------------------------------------
// Pack x [b][c1][64][64] f32 -> xT[b][c1c][rowp 76][colp 80][c1i 32] bf16,
// zero-padded halo (rowp = row+6, colp = ic+8), chunk swizzle baked in.
// ---------------------------------------------------------------------------
__global__ __launch_bounds__(256) void pack_xt_kernel(
    const float* __restrict__ x, unsigned short* __restrict__ xT) {
  const int blk = blockIdx.x;  // (b*8 + c1c)*76 + rowp ; 4864 blocks
  const int rowp = blk % 76;
  const int bc = blk / 76;
  const int c1c = bc & 7, b = bc >> 3;
  const int row = rowp - 6;
  const bool rok = (unsigned)row < 64u;
  unsigned short* dst = xT + (size_t)blk * 2560;
  const float* srcb = x + (size_t)(b * 256 + c1c * 32) * 4096 +
                      (rok ? row * 64 : 0);
#pragma unroll
  for (int e = 0; e < 10; ++e) {
    const int idx = e * 256 + threadIdx.x;  // 0..2559
    const int colp = idx >> 5, c1i = idx & 31;
    const int ic = colp - 8;
    const float v = (rok && (unsigned)ic < 64u) ? srcb[(size_t)c1i * 4096 + ic] : 0.f;
    dst[colp * 32 + ((((c1i >> 3) ^ swz4(colp)) << 3)) + (c1i & 7)] = f2bf(v);
  }
}

// ---------------------------------------------------------------------------
// K-split implicit-GEMM conv, partials atomicAdd'ed into pre-zeroed out.
// Block: 256 thr (4 waves 2M x 2N), tile 128 c2 x 256 sp (4h x 64w),
// wave tile 64 x 128 (43.7 FLOP/LDS-byte). K-half = 676 steps.
// Grid 512 = 2 Khalf x 2 c2t x 8 b x 16 hq -> 2 blocks/CU.
// Phase (1 kw step): S1 {16 ds_read->regs} | W-round + A-glds(s+2, 3-buf) |
// bar | 16 MFMA pure-reg | vmwait<2|3> | bar.
// ---------------------------------------------------------------------------
__global__ __launch_bounds__(256, 2) void conv9_kernel(
    const unsigned short* __restrict__ Wp, const unsigned short* __restrict__ xT,
    float* __restrict__ out) {
  __shared__ __align__(16) unsigned short Abuf[3][4096];   // 3 x 8 KiB
  __shared__ __align__(16) unsigned short Wbuf[2][10240];  // 2 x 20 KiB

  const int tid = threadIdx.x;
  const int bid = blockIdx.x;
  const int b = bid & 7;  // XCD-aware: blocks on XCD k share batch image k
  const int rest = bid >> 3;          // 0..63
  const int hq = rest & 15;           // h-quad
  const int c2t = (rest >> 4) & 1;
  const int kHalf = rest >> 5;
  const int h0 = hq * 4;

  const int wid = tid >> 6, lane = tid & 63;
  const int wr = wid >> 1, wc = wid & 1;
  const int l31 = lane & 31, hi2 = lane >> 5;

  // A fragment byte offsets in an 8 KiB tile: m = wr*64 + mt*32 + l31
  int aoffs[2][2];
#pragma unroll
  for (int mt = 0; mt < 2; ++mt)
#pragma unroll
    for (int ks = 0; ks < 2; ++ks) {
      const int m = wr * 64 + mt * 32 + l31;
      aoffs[mt][ks] = m * 64 + (((ks * 2 + hi2) ^ swz4(m)) << 4);
    }
  // B spatial decomposition: n = wc*128 + nt*32 + l31 (0..255 = 4h x 64w)
  int ndh[4], nwl[4];
#pragma unroll
  for (int nt = 0; nt < 4; ++nt) {
    const int n = wc * 128 + nt * 32 + l31;
    ndh[nt] = n >> 6;
    nwl[nt] = n & 63;
  }

  const int tid8 = tid * 8;
  const int widA = wid * 512;  // ush units (wave-linear glds dst)

  const size_t c2base = (size_t)c2t * 1352;
  const int base676 = kHalf * 676;
  const int base52 = kHalf * 52;
  const int bc8 = b * 8;
  const char* WpB = (const char*)Wp;
  const char* Abase = (const char*)&Abuf[0][0];
  unsigned short* AbaseU = &Abuf[0][0];

  auto wtileG = [&](int T) -> const unsigned short* {  // T global 0..103
    const int kh = T >> 3, c1c = T & 7;
    return xT + (size_t)((bc8 + c1c) * 76 + h0 + kh) * 2560;
  };

  f32x16 acc[2][4];
#pragma unroll
  for (int i = 0; i < 2; ++i)
#pragma unroll
    for (int j = 0; j < 4; ++j)
#pragma unroll
      for (int r = 0; r < 16; ++r) acc[i][j][r] = 0.f;

  // runtime-rotated LDS byte offsets for the 3 A buffers
  int aoff0 = 0, aoff1 = 8192, aoff2 = 16384;
  unsigned short* wcurU = &Wbuf[0][0];
  unsigned short* wnxtU = &Wbuf[1][0];

  // ---- prologue: W(tile0) -> wcur (5 rounds); A steps 0,1 -> bufs 0,1
  {
    const unsigned short* ws0 = wtileG(base52);
#pragma unroll
    for (int r = 0; r < 5; ++r)
      glds16(ws0 + r * 2048 + tid8, wcurU + r * 2048 + widA);
    const unsigned short* at0 =
        (const unsigned short*)(WpB + ((c2base + (size_t)base676) << 13));
    const unsigned short* at1 =
        (const unsigned short*)(WpB + ((c2base + (size_t)(base676 + 1)) << 13));
    glds16(at0 + tid8, AbaseU + widA);
    glds16(at0 + 2048 + tid8, AbaseU + 2048 + widA);
    glds16(at1 + tid8, AbaseU + 4096 + widA);
    glds16(at1 + 2048 + tid8, AbaseU + 4096 + 2048 + widA);
    vmwait<2>();  // A(0), W(0) landed; A(1) in flight
    __builtin_amdgcn_s_barrier();
    __builtin_amdgcn_sched_barrier(0);
  }

#define STEP(Q)                                                               \
  {                                                                           \
    /* S1: 16 fragment ds_reads into phase-local regs */                      \
    const char* ab = Abase + aoff0;                                           \
    const char* wb = (const char*)wcurU;                                      \
    bf16x8 rA[2][2], rB[2][4];                                                \
    _Pragma("unroll") for (int ks = 0; ks < 2; ++ks) {                        \
      rA[ks][0] = *(const bf16x8*)(ab + aoffs[0][ks]);                        \
      rA[ks][1] = *(const bf16x8*)(ab + aoffs[1][ks]);                        \
      _Pragma("unroll") for (int nt = 0; nt < 4; ++nt) {                      \
        const int col = nwl[nt] + (Q) + 2;                                    \
        rB[ks][nt] = *(const bf16x8*)(wb + (ndh[nt] * 80 + col) * 64 +        \
                                      (((ks * 2 + hi2) ^ swz4(col)) << 4));   \
      }                                                                       \
    }                                                                         \
    /* W round (next tile) on phases 1..5 */                                  \
    if ((Q) >= 1 && (Q) <= 5)                                                 \
      glds16(wsrc + ((Q) - 1) * 2048 + tid8, wnxtU + ((Q) - 1) * 2048 + widA);\
    /* A prefetch depth-2 -> third buffer */                                  \
    {                                                                         \
      int lp = t13 + (Q) + 2;                                                 \
      if (lp >= 676) lp -= 676;                                               \
      const unsigned short* at = (const unsigned short*)(                     \
          WpB + ((c2base + (size_t)(base676 + lp)) << 13));                   \
      unsigned short* ad = AbaseU + (aoff2 >> 1);                             \
      glds16(at + tid8, ad + widA);                                           \
      glds16(at + 2048 + tid8, ad + 2048 + widA);                             \
    }                                                                         \
    asm volatile("" ::: "memory");                                            \
    __builtin_amdgcn_s_barrier();                                             \
    __builtin_amdgcn_sched_barrier(0);                                        \
    __builtin_amdgcn_s_setprio(1);                                            \
    _Pragma("unroll") for (int ks = 0; ks < 2; ++ks)                          \
        _Pragma("unroll") for (int nt = 0; nt < 4; ++nt) {                    \
      acc[0][nt] = __builtin_amdgcn_mfma_f32_32x32x16_bf16(                   \
          rA[ks][0], rB[ks][nt], acc[0][nt], 0, 0, 0);                        \
      acc[1][nt] = __builtin_amdgcn_mfma_f32_32x32x16_bf16(                   \
          rA[ks][1], rB[ks][nt], acc[1][nt], 0, 0, 0);                        \
    }                                                                         \
    __builtin_amdgcn_s_setprio(0);                                            \
    vmwait<(((Q) >= 1 && (Q) <= 5) ? 3 : 2)>();                               \
    __builtin_amdgcn_s_barrier();                                             \
    __builtin_amdgcn_sched_barrier(0);                                        \
    const int ta_ = aoff0; aoff0 = aoff1; aoff1 = aoff2; aoff2 = ta_;         \
  }

  for (int t = 0; t < 52; ++t) {
    const int tn = (t + 1 == 52) ? 0 : t + 1;  // tail wraps (harmless staging)
    const unsigned short* wsrc = wtileG(base52 + tn);
    const int t13 = t * 13;
    STEP(0) STEP(1) STEP(2) STEP(3) STEP(4) STEP(5) STEP(6)
    STEP(7) STEP(8) STEP(9) STEP(10) STEP(11) STEP(12)
    unsigned short* tw = wcurU; wcurU = wnxtU; wnxtU = tw;
  }
#undef STEP

  vmwait<0>();  // drain dangling prefetches

  // ---- epilogue: atomicAdd raw partials into pre-zeroed out.
  // 32x32 C/D layout (m74/m101): col = lane&31, row = (r&3)+8*(r>>2)+4*(lane>>5)
#pragma unroll
  for (int mt = 0; mt < 2; ++mt) {
#pragma unroll
    for (int nt = 0; nt < 4; ++nt) {
      const int n = wc * 128 + nt * 32 + l31;
      const int hh = h0 + (n >> 6), ww = n & 63;
#pragma unroll
      for (int r = 0; r < 16; ++r) {
        const int mloc = (r & 3) + 8 * (r >> 2) + 4 * hi2;
        const int c2l = wr * 64 + mt * 32 + mloc;
        atomicAdd(&out[((size_t)(b * 256 + c2t * 128 + c2l)) * 4096 +
                       hh * 64 + ww],
                  acc[mt][nt][r]);
      }
    }
  }
}

// ---------------------------------------------------------------------------
// Elementwise BN (inference) + SiLU applied in-place to the raw conv sums.
// ---------------------------------------------------------------------------
__global__ __launch_bounds__(256) void bn_silu_kernel(
    const float* __restrict__ gamma, const float* __restrict__ beta,
    const float* __restrict__ mean, const float* __restrict__ var,
    float* __restrict__ out) {
  const int i = blockIdx.x * 256 + threadIdx.x;  // 0..524287
  f32x4* o4 = (f32x4*)out;
#pragma unroll
  for (int rr = 0; rr < 4; ++rr) {
    const int i4 = i + rr * 524288;  // 2,097,152 f32x4 total
    f32x4 v = o4[i4];
    const int c2 = (i4 >> 10) & 255;
    const float inv = gamma[c2] * rsqrtf(var[c2] + EPS);
    const float sh = beta[c2] - mean[c2] * inv;
#pragma unroll
    for (int j = 0; j < 4; ++j) {
      const float y = v[j] * inv + sh;
      v[j] = y / (1.f + __expf(-y));
    }
    o4[i4] = v;
  }
}

// ---------------------------------------------------------------------------
// Safety-net fallback if workspace is too small for packed buffers.
// ---------------------------------------------------------------------------
__global__ void naive_conv_kernel(
    const float* __restrict__ x, const float* __restrict__ W,
    const float* __restrict__ gamma, const float* __restrict__ beta,
    const float* __restrict__ mean, const float* __restrict__ var,
    float* __restrict__ out) {
  const int idx = blockIdx.x * 256 + threadIdx.x;
  if (idx >= 8 * 256 * 64 * 64) return;
  const int w = idx & 63, h = (idx >> 6) & 63;
  const int c2 = (idx >> 12) & 255, b = idx >> 20;
  float s = 0.f;
  for (int c1 = 0; c1 < 256; ++c1) {
    const float* xp = x + ((size_t)(b * 256 + c1) * 4096);
    const float* wp = W + ((size_t)(c2 * 256 + c1) * 169);
    for (int kh = 0; kh < 13; ++kh) {
      const int r = h + kh - 6;
      if ((unsigned)r >= 64u) continue;
      for (int kw = 0; kw < 13; ++kw) {
        const int c = w + kw - 6;
        if ((unsigned)c >= 64u) continue;
        s += xp[r * 64 + c] * wp[kh * 13 + kw];
      }
    }
  }
  const float inv = gamma[c2] * rsqrtf(var[c2] + EPS);
  const float y = s * inv + (beta[c2] - mean[c2] * inv);
  out[idx] = y / (1.f + __expf(-y));
}

extern "C" void kernel_launch(void* const* d_in, const int* in_sizes, int n_in,
                              void* d_out, int out_size, void* d_ws, size_t ws_size,
                              hipStream_t stream) {
  const float* x = (const float*)d_in[0];
  const float* W = (const float*)d_in[1];
  const float* gamma = (const float*)d_in[2];
  const float* beta = (const float*)d_in[3];
  const float* mean = (const float*)d_in[4];
  const float* var = (const float*)d_in[5];
  float* out = (float*)d_out;

  const size_t WP_BYTES = (size_t)256 * 43264 * 2;  // 22,151,168
  const size_t XT_BYTES = (size_t)12455424 * 2;     // 24,910,848

  if (ws_size >= WP_BYTES + XT_BYTES) {
    unsigned short* Wp = (unsigned short*)d_ws;
    unsigned short* xT = (unsigned short*)((char*)d_ws + WP_BYTES);
    hipMemsetAsync(out, 0, (size_t)out_size * sizeof(float), stream);
    pack_w_kernel<<<256 * 13, 256, 0, stream>>>(W, Wp);
    pack_xt_kernel<<<8 * 8 * 76, 256, 0, stream>>>(x, xT);
    conv9_kernel<<<512, 256, 0, stream>>>(Wp, xT, out);
    bn_silu_kernel<<<2048, 256, 0, stream>>>(gamma, beta, mean, var, out);
  } else {
    naive_conv_kernel<<<(8 * 256 * 64 * 64 + 255) / 256, 256, 0, stream>>>(
        x, W, gamma, beta, mean, var, out);
  }
}

// Round 10
// 615.173 us; speedup vs baseline: 1.4152x; 1.1189x over previous
//
#include <hip/hip_runtime.h>
#include <stdint.h>

#define EPS 1e-5f

typedef __attribute__((ext_vector_type(8))) __bf16 bf16x8;
typedef __attribute__((ext_vector_type(16))) float f32x16;

__device__ __forceinline__ int swz4(int r) { return (r ^ (r >> 2)) & 3; }

__device__ __forceinline__ unsigned short f2bf(float f) {
  union { float f; unsigned u; } v; v.f = f;
  unsigned r = v.u + 0x7fffu + ((v.u >> 16) & 1u);
  return (unsigned short)(r >> 16);
}

__device__ __forceinline__ void glds16(const unsigned short* g, unsigned short* l) {
  __builtin_amdgcn_global_load_lds(
      (const __attribute__((address_space(1))) void*)g,
      (__attribute__((address_space(3))) void*)l, 16, 0, 0);
}
__device__ __forceinline__ void glds4(const unsigned short* g, unsigned short* l) {
  __builtin_amdgcn_global_load_lds(
      (const __attribute__((address_space(1))) void*)g,
      (__attribute__((address_space(3))) void*)l, 4, 0, 0);
}

template <int N>
__device__ __forceinline__ void vmwait() {
  asm volatile("s_waitcnt vmcnt(%0)" ::"n"(N) : "memory");
}

// ---------------------------------------------------------------------------
// Pack W [c2][c1][13][13] f32 -> bf16 per-K-step tiles = exact linear LDS
// image of the A tile (chunk swizzle baked in).
// K order: k = ((kh*8 + c1c)*13 + kw)*32 + c1i
// ---------------------------------------------------------------------------
__global__ __launch_bounds__(256) void pack_w_kernel(
    const float* __restrict__ W, unsigned short* __restrict__ Wp) {
  const int blk = blockIdx.x;  // c2*13 + kh
  const int c2 = blk / 13, kh = blk - c2 * 13;
  const int c1 = threadIdx.x;
  const int c2t = c2 >> 7, m = c2 & 127;
  const int c1c = c1 >> 5, c1i = c1 & 31;
  const float* src = W + (((size_t)(c2 * 256 + c1)) * 13 + kh) * 13;
  const int rowoff = (((c1i >> 3) ^ swz4(m)) << 3) + (c1i & 7);
#pragma unroll
  for (int kw = 0; kw < 13; ++kw) {
    const int ks = (kh * 8 + c1c) * 13 + kw;
    const size_t dst = (((size_t)c2t * 1352 + ks) * 128 + m) * 32 + rowoff;
    Wp[dst] = f2bf(src[kw]);
  }
}

// ---------------------------------------------------------------------------
// Pack x [b][c1][64][64] f32 -> xT[b][c1c][rowp 76][colp 80][c1i 32] bf16,
// zero-padded halo (rowp = row+6, colp = ic+8), chunk swizzle baked in.
// ---------------------------------------------------------------------------
__global__ __launch_bounds__(256) void pack_xt_kernel(
    const float* __restrict__ x, unsigned short* __restrict__ xT) {
  const int blk = blockIdx.x;  // (b*8 + c1c)*76 + rowp ; 4864 blocks
  const int rowp = blk % 76;
  const int bc = blk / 76;
  const int c1c = bc & 7, b = bc >> 3;
  const int row = rowp - 6;
  const bool rok = (unsigned)row < 64u;
  unsigned short* dst = xT + (size_t)blk * 2560;
  const float* srcb = x + (size_t)(b * 256 + c1c * 32) * 4096 +
                      (rok ? row * 64 : 0);
#pragma unroll
  for (int e = 0; e < 10; ++e) {
    const int idx = e * 256 + threadIdx.x;  // 0..2559
    const int colp = idx >> 5, c1i = idx & 31;
    const int ic = colp - 8;
    const float v = (rok && (unsigned)ic < 64u) ? srcb[(size_t)c1i * 4096 + ic] : 0.f;
    dst[colp * 32 + ((((c1i >> 3) ^ swz4(colp)) << 3)) + (c1i & 7)] = f2bf(v);
  }
}

// ---------------------------------------------------------------------------
// Implicit-GEMM conv + BN + SiLU.  (conv6 + depth-2 A prefetch, counted drains)
// Block: 256 thr (4 waves 2M x 2N), tile 128 c2 x 128 sp (2h x 64w).
// Wave tile 64x64 via 32x32x16 MFMA. Grid 512 -> 2 independent blocks/CU.
// Phase: S1 {16 ds_read -> regs} | W round + A glds(p+2, 3-buf rotate) |
// bar | pure-reg MFMA | vmwait<this-phase-issues> | bar.
// ---------------------------------------------------------------------------
__global__ __launch_bounds__(256, 2) void conv10_kernel(
    const unsigned short* __restrict__ Wp, const unsigned short* __restrict__ xT,
    const float* __restrict__ gamma, const float* __restrict__ beta,
    const float* __restrict__ mean, const float* __restrict__ var,
    float* __restrict__ out) {
  __shared__ __align__(16) unsigned short Abuf[3][8192];  // 3 x 16 KiB (2 tiles each)
  __shared__ __align__(16) unsigned short Wbuf[2][5120];  // 2 x 10 KiB (2 rows)
  __shared__ float s_scale[128], s_shift[128];

  const int tid = threadIdx.x;
  const int bid = blockIdx.x;
  const int b = bid & 7;  // XCD-aware: blocks on XCD k share batch image k
  const int h0 = ((bid >> 3) & 31) * 2;
  const int c2t = bid >> 8;

  const int wid = tid >> 6, lane = tid & 63;
  const int wr = wid >> 1, wc = wid & 1;
  const int l31 = lane & 31, hi2 = lane >> 5;

  if (tid < 128) {
    const int c2 = c2t * 128 + tid;
    const float inv = gamma[c2] * rsqrtf(var[c2] + EPS);
    s_scale[tid] = inv;
    s_shift[tid] = beta[c2] - mean[c2] * inv;
  }

  // A-fragment byte offsets within a 4096-ushort (8 KiB) step-tile
  int aoffs[2][2];
#pragma unroll
  for (int mt = 0; mt < 2; ++mt)
#pragma unroll
    for (int ks = 0; ks < 2; ++ks) {
      const int m = wr * 64 + mt * 32 + l31;
      aoffs[mt][ks] = m * 64 + (((ks * 2 + hi2) ^ swz4(m)) << 4);
    }
  int ndh[2], nwl[2];
#pragma unroll
  for (int nt = 0; nt < 2; ++nt) {
    const int n = wc * 64 + nt * 32 + l31;
    ndh[nt] = n >> 6;
    nwl[nt] = n & 63;
  }

  const int tid8 = tid * 8, tid2 = tid * 2;
  const int widA = wid * 512, wid128 = wid * 128;

  const size_t c2base = (size_t)c2t * 1352;
  const int bc8 = b * 8;
  const char* Abase = (const char*)&Abuf[0][0];
  unsigned short* AbaseU = &Abuf[0][0];

  auto wtile = [&](int T) -> const unsigned short* {
    const int kh = T >> 3, c1c = T & 7;
    return xT + (size_t)((bc8 + c1c) * 76 + h0 + kh) * 2560;
  };

  f32x16 acc[2][2];
#pragma unroll
  for (int i = 0; i < 2; ++i)
#pragma unroll
    for (int j = 0; j < 2; ++j)
#pragma unroll
      for (int r = 0; r < 16; ++r) acc[i][j][r] = 0.f;

  // fragment registers for one phase (2 kw-steps): [step][ks][mt/nt]
  bf16x8 rA[2][2][2], rB[2][2][2];

  // runtime-rotated byte offsets of the 3 A buffers (16 KiB each)
  int aRd = 0, aMid = 16384, aWr = 32768;

  // ---- prologue: A(ph0)->buf0, W(tile0)->Wbuf[0], A(ph1)->buf1
  {
    const unsigned short* at0 = Wp + (c2base << 12);
    const unsigned short* at1 = Wp + ((c2base + 1) << 12);
    glds16(at0 + tid8, AbaseU + widA);
    glds16(at0 + 2048 + tid8, AbaseU + 2048 + widA);
    glds16(at1 + tid8, AbaseU + 4096 + widA);
    glds16(at1 + 2048 + tid8, AbaseU + 6144 + widA);
    const unsigned short* ws = wtile(0);
    glds16(ws + tid8, &Wbuf[0][0] + widA);
    glds16(ws + 2048 + tid8, &Wbuf[0][2048] + widA);
    glds4(ws + 4096 + tid2, &Wbuf[0][4096] + wid128);
    glds4(ws + 4608 + tid2, &Wbuf[0][4608] + wid128);
    const unsigned short* at2 = Wp + ((c2base + 2) << 12);
    const unsigned short* at3 = Wp + ((c2base + 3) << 12);
    unsigned short* ad1 = AbaseU + 8192;
    glds16(at2 + tid8, ad1 + widA);
    glds16(at2 + 2048 + tid8, ad1 + 2048 + widA);
    glds16(at3 + tid8, ad1 + 4096 + widA);
    glds16(at3 + 2048 + tid8, ad1 + 6144 + widA);
    vmwait<4>();  // A(ph0)+W(t0) landed; A(ph1) in flight
    __builtin_amdgcn_s_barrier();
    __builtin_amdgcn_sched_barrier(0);
  }

// one phase = 2 kw steps. S1: 16 ds_read -> regs; W round + A glds(p+2);
// bar; pure-reg MFMA x16; vmwait<4|5|6> (this phase's issues stay); bar.
#define PHASE(PH, KWA, WBA, KWB, WBB, WRT, WSRCP, WDB)                        \
  {                                                                           \
    /* ---- S1: fragment reads for THIS phase (buf filled 2 phases ago) */    \
    {                                                                         \
      const char* abA = Abase + aRd;                                          \
      const char* abB = abA + 8192;                                           \
      const char* wbA = (const char*)&Wbuf[(WBA)][0];                         \
      const char* wbB = (const char*)&Wbuf[(WBB)][0];                         \
      _Pragma("unroll") for (int ks = 0; ks < 2; ++ks) {                      \
        rA[0][ks][0] = *(const bf16x8*)(abA + aoffs[0][ks]);                  \
        rA[0][ks][1] = *(const bf16x8*)(abA + aoffs[1][ks]);                  \
        rA[1][ks][0] = *(const bf16x8*)(abB + aoffs[0][ks]);                  \
        rA[1][ks][1] = *(const bf16x8*)(abB + aoffs[1][ks]);                  \
        _Pragma("unroll") for (int nt = 0; nt < 2; ++nt) {                    \
          const int colA = nwl[nt] + (KWA) + 2;                               \
          rB[0][ks][nt] = *(const bf16x8*)(                                   \
              wbA + (ndh[nt] * 80 + colA) * 64 +                              \
              (((ks * 2 + hi2) ^ swz4(colA)) << 4));                          \
          const int colB = nwl[nt] + (KWB) + 2;                               \
          rB[1][ks][nt] = *(const bf16x8*)(                                   \
              wbB + (ndh[nt] * 80 + colB) * 64 +                              \
              (((ks * 2 + hi2) ^ swz4(colB)) << 4));                          \
        }                                                                     \
      }                                                                       \
    }                                                                         \
    /* ---- W round for next tile */                                          \
    if ((WRT) == 1) glds16((WSRCP) + tid8, &Wbuf[(WDB)][0] + widA);           \
    if ((WRT) == 2)                                                           \
      glds16((WSRCP) + 2048 + tid8, &Wbuf[(WDB)][2048] + widA);               \
    if ((WRT) == 3) {                                                         \
      glds4((WSRCP) + 4096 + tid2, &Wbuf[(WDB)][4096] + wid128);              \
      glds4((WSRCP) + 4608 + tid2, &Wbuf[(WDB)][4608] + wid128);              \
    }                                                                         \
    /* ---- A prefetch DEPTH-2: steps for phase p+2 -> rotating 3rd buf */    \
    {                                                                         \
      int sn0 = S0 + 2 * (PH) + 4;                                            \
      if (sn0 >= 1352) sn0 -= 1352;                                           \
      int sn1 = sn0 + 1;                                                      \
      if (sn1 >= 1352) sn1 -= 1352;                                           \
      const unsigned short* at0 = Wp + ((c2base + (size_t)sn0) << 12);        \
      const unsigned short* at1 = Wp + ((c2base + (size_t)sn1) << 12);        \
      unsigned short* ad = AbaseU + (aWr >> 1);                               \
      glds16(at0 + tid8, ad + widA);                                          \
      glds16(at0 + 2048 + tid8, ad + 2048 + widA);                            \
      glds16(at1 + tid8, ad + 4096 + widA);                                   \
      glds16(at1 + 2048 + tid8, ad + 6144 + widA);                            \
    }                                                                         \
    asm volatile("" ::: "memory");                                            \
    __builtin_amdgcn_s_barrier();                                             \
    __builtin_amdgcn_sched_barrier(0);                                        \
    /* ---- pure-register MFMA cluster */                                     \
    {                                                                         \
      __builtin_amdgcn_s_setprio(1);                                          \
      _Pragma("unroll") for (int s = 0; s < 2; ++s)                           \
          _Pragma("unroll") for (int ks = 0; ks < 2; ++ks) {                  \
        acc[0][0] = __builtin_amdgcn_mfma_f32_32x32x16_bf16(                  \
            rA[s][ks][0], rB[s][ks][0], acc[0][0], 0, 0, 0);                  \
        acc[0][1] = __builtin_amdgcn_mfma_f32_32x32x16_bf16(                  \
            rA[s][ks][0], rB[s][ks][1], acc[0][1], 0, 0, 0);                  \
        acc[1][0] = __builtin_amdgcn_mfma_f32_32x32x16_bf16(                  \
            rA[s][ks][1], rB[s][ks][0], acc[1][0], 0, 0, 0);                  \
        acc[1][1] = __builtin_amdgcn_mfma_f32_32x32x16_bf16(                  \
            rA[s][ks][1], rB[s][ks][1], acc[1][1], 0, 0, 0);                  \
      }                                                                       \
      __builtin_amdgcn_s_setprio(0);                                          \
    }                                                                         \
    /* drain: keep ONLY this phase's issues in flight (A(p+2) + W) */         \
    vmwait<((WRT) == 0 ? 4 : ((WRT) == 3 ? 6 : 5))>();                        \
    __builtin_amdgcn_s_barrier();                                             \
    { const int t_ = aRd; aRd = aMid; aMid = aWr; aWr = t_; }                 \
  }

  // 26 u-iterations x 4 tiles (52 steps, 26 phases) — W parities static
  for (int u = 0; u < 26; ++u) {
    const int S0 = u * 52;
    const int Tb = u * 4;
    const unsigned short* wt1 = wtile(Tb + 1);
    const unsigned short* wt2 = wtile(Tb + 2);
    const unsigned short* wt3 = wtile(Tb + 3);
    const unsigned short* wt4 = wtile((Tb + 4 == 104) ? 0 : Tb + 4);
    PHASE(0, 0, 0, 1, 0, 0, wt1, 1)
    PHASE(1, 2, 0, 3, 0, 0, wt1, 1)
    PHASE(2, 4, 0, 5, 0, 0, wt1, 1)
    PHASE(3, 6, 0, 7, 0, 1, wt1, 1)
    PHASE(4, 8, 0, 9, 0, 2, wt1, 1)
    PHASE(5, 10, 0, 11, 0, 3, wt1, 1)
    PHASE(6, 12, 0, 0, 1, 0, wt1, 1)
    PHASE(7, 1, 1, 2, 1, 0, wt2, 0)
    PHASE(8, 3, 1, 4, 1, 0, wt2, 0)
    PHASE(9, 5, 1, 6, 1, 1, wt2, 0)
    PHASE(10, 7, 1, 8, 1, 2, wt2, 0)
    PHASE(11, 9, 1, 10, 1, 3, wt2, 0)
    PHASE(12, 11, 1, 12, 1, 0, wt2, 0)
    PHASE(13, 0, 0, 1, 0, 0, wt3, 1)
    PHASE(14, 2, 0, 3, 0, 0, wt3, 1)
    PHASE(15, 4, 0, 5, 0, 0, wt3, 1)
    PHASE(16, 6, 0, 7, 0, 1, wt3, 1)
    PHASE(17, 8, 0, 9, 0, 2, wt3, 1)
    PHASE(18, 10, 0, 11, 0, 3, wt3, 1)
    PHASE(19, 12, 0, 0, 1, 0, wt3, 1)
    PHASE(20, 1, 1, 2, 1, 0, wt4, 0)
    PHASE(21, 3, 1, 4, 1, 0, wt4, 0)
    PHASE(22, 5, 1, 6, 1, 1, wt4, 0)
    PHASE(23, 7, 1, 8, 1, 2, wt4, 0)
    PHASE(24, 9, 1, 10, 1, 3, wt4, 0)
    PHASE(25, 11, 1, 12, 1, 0, wt4, 0)
  }
#undef PHASE

  vmwait<0>();  // drain dangling prefetches

  // ---- epilogue: BN + SiLU.
  // 32x32 C/D layout (m74/m101): col = lane&31, row = (r&3)+8*(r>>2)+4*(lane>>5)
#pragma unroll
  for (int mt = 0; mt < 2; ++mt) {
#pragma unroll
    for (int nt = 0; nt < 2; ++nt) {
      const int n = wc * 64 + nt * 32 + l31;
      const int hh = h0 + (n >> 6), ww = n & 63;
#pragma unroll
      for (int r = 0; r < 16; ++r) {
        const int mloc = (r & 3) + 8 * (r >> 2) + 4 * hi2;
        const int c2l = wr * 64 + mt * 32 + mloc;
        const float y = acc[mt][nt][r] * s_scale[c2l] + s_shift[c2l];
        out[((size_t)(b * 256 + c2t * 128 + c2l)) * 4096 + hh * 64 + ww] =
            y / (1.f + __expf(-y));
      }
    }
  }
}

// ---------------------------------------------------------------------------
// Safety-net fallback if workspace is too small for packed buffers.
// ---------------------------------------------------------------------------
__global__ void naive_conv_kernel(
    const float* __restrict__ x, const float* __restrict__ W,
    const float* __restrict__ gamma, const float* __restrict__ beta,
    const float* __restrict__ mean, const float* __restrict__ var,
    float* __restrict__ out) {
  const int idx = blockIdx.x * 256 + threadIdx.x;
  if (idx >= 8 * 256 * 64 * 64) return;
  const int w = idx & 63, h = (idx >> 6) & 63;
  const int c2 = (idx >> 12) & 255, b = idx >> 20;
  float s = 0.f;
  for (int c1 = 0; c1 < 256; ++c1) {
    const float* xp = x + ((size_t)(b * 256 + c1) * 4096);
    const float* wp = W + ((size_t)(c2 * 256 + c1) * 169);
    for (int kh = 0; kh < 13; ++kh) {
      const int r = h + kh - 6;
      if ((unsigned)r >= 64u) continue;
      for (int kw = 0; kw < 13; ++kw) {
        const int c = w + kw - 6;
        if ((unsigned)c >= 64u) continue;
        s += xp[r * 64 + c] * wp[kh * 13 + kw];
      }
    }
  }
  const float inv = gamma[c2] * rsqrtf(var[c2] + EPS);
  const float y = s * inv + (beta[c2] - mean[c2] * inv);
  out[idx] = y / (1.f + __expf(-y));
}

extern "C" void kernel_launch(void* const* d_in, const int* in_sizes, int n_in,
                              void* d_out, int out_size, void* d_ws, size_t ws_size,
                              hipStream_t stream) {
  const float* x = (const float*)d_in[0];
  const float* W = (const float*)d_in[1];
  const float* gamma = (const float*)d_in[2];
  const float* beta = (const float*)d_in[3];
  const float* mean = (const float*)d_in[4];
  const float* var = (const float*)d_in[5];
  float* out = (float*)d_out;

  const size_t WP_BYTES = (size_t)256 * 43264 * 2;  // 22,151,168
  const size_t XT_BYTES = (size_t)12455424 * 2;     // 24,910,848

  if (ws_size >= WP_BYTES + XT_BYTES) {
    unsigned short* Wp = (unsigned short*)d_ws;
    unsigned short* xT = (unsigned short*)((char*)d_ws + WP_BYTES);
    pack_w_kernel<<<256 * 13, 256, 0, stream>>>(W, Wp);
    pack_xt_kernel<<<8 * 8 * 76, 256, 0, stream>>>(x, xT);
    conv10_kernel<<<512, 256, 0, stream>>>(Wp, xT, gamma, beta, mean, var, out);
  } else {
    naive_conv_kernel<<<(8 * 256 * 64 * 64 + 255) / 256, 256, 0, stream>>>(
        x, W, gamma, beta, mean, var, out);
  }
}

// Round 11
// 606.563 us; speedup vs baseline: 1.4353x; 1.0142x over previous
//
#include <hip/hip_runtime.h>
#include <stdint.h>

#define EPS 1e-5f

typedef __attribute__((ext_vector_type(8))) __bf16 bf16x8;
typedef __attribute__((ext_vector_type(16))) float f32x16;

__device__ __forceinline__ int swz4(int r) { return (r ^ (r >> 2)) & 3; }

__device__ __forceinline__ unsigned short f2bf(float f) {
  union { float f; unsigned u; } v; v.f = f;
  unsigned r = v.u + 0x7fffu + ((v.u >> 16) & 1u);
  return (unsigned short)(r >> 16);
}

__device__ __forceinline__ void glds16(const unsigned short* g, unsigned short* l) {
  __builtin_amdgcn_global_load_lds(
      (const __attribute__((address_space(1))) void*)g,
      (__attribute__((address_space(3))) void*)l, 16, 0, 0);
}
__device__ __forceinline__ void glds4(const unsigned short* g, unsigned short* l) {
  __builtin_amdgcn_global_load_lds(
      (const __attribute__((address_space(1))) void*)g,
      (__attribute__((address_space(3))) void*)l, 4, 0, 0);
}

template <int N>
__device__ __forceinline__ void vmwait() {
  asm volatile("s_waitcnt vmcnt(%0)" ::"n"(N) : "memory");
}

// ---------------------------------------------------------------------------
// Pack W [c2][c1][13][13] f32 -> bf16 per-K-step tiles = exact linear LDS
// image of the A tile (chunk swizzle baked in).
// K order: k = ((kh*8 + c1c)*13 + kw)*32 + c1i
// ---------------------------------------------------------------------------
__global__ __launch_bounds__(256) void pack_w_kernel(
    const float* __restrict__ W, unsigned short* __restrict__ Wp) {
  const int blk = blockIdx.x;  // c2*13 + kh
  const int c2 = blk / 13, kh = blk - c2 * 13;
  const int c1 = threadIdx.x;
  const int c2t = c2 >> 7, m = c2 & 127;
  const int c1c = c1 >> 5, c1i = c1 & 31;
  const float* src = W + (((size_t)(c2 * 256 + c1)) * 13 + kh) * 13;
  const int rowoff = (((c1i >> 3) ^ swz4(m)) << 3) + (c1i & 7);
#pragma unroll
  for (int kw = 0; kw < 13; ++kw) {
    const int ks = (kh * 8 + c1c) * 13 + kw;
    const size_t dst = (((size_t)c2t * 1352 + ks) * 128 + m) * 32 + rowoff;
    Wp[dst] = f2bf(src[kw]);
  }
}

// ---------------------------------------------------------------------------
// Pack x [b][c1][64][64] f32 -> xT[b][c1c][rowp 76][colp 80][c1i 32] bf16,
// zero-padded halo (rowp = row+6, colp = ic+8), chunk swizzle baked in.
// ---------------------------------------------------------------------------
__global__ __launch_bounds__(256) void pack_xt_kernel(
    const float* __restrict__ x, unsigned short* __restrict__ xT) {
  const int blk = blockIdx.x;  // (b*8 + c1c)*76 + rowp ; 4864 blocks
  const int rowp = blk % 76;
  const int bc = blk / 76;
  const int c1c = bc & 7, b = bc >> 3;
  const int row = rowp - 6;
  const bool rok = (unsigned)row < 64u;
  unsigned short* dst = xT + (size_t)blk * 2560;
  const float* srcb = x + (size_t)(b * 256 + c1c * 32) * 4096 +
                      (rok ? row * 64 : 0);
#pragma unroll
  for (int e = 0; e < 10; ++e) {
    const int idx = e * 256 + threadIdx.x;  // 0..2559
    const int colp = idx >> 5, c1i = idx & 31;
    const int ic = colp - 8;
    const float v = (rok && (unsigned)ic < 64u) ? srcb[(size_t)c1i * 4096 + ic] : 0.f;
    dst[colp * 32 + ((((c1i >> 3) ^ swz4(colp)) << 3)) + (c1i & 7)] = f2bf(v);
  }
}

// ---------------------------------------------------------------------------
// Implicit-GEMM conv + BN + SiLU.  (conv10 + in-phase interleave, 1 bar/phase)
// Block: 256 thr (4 waves 2M x 2N), tile 128 c2 x 128 sp (2h x 64w).
// Wave tile 64x64 via 32x32x16 MFMA. Grid 512 -> 2 independent blocks/CU.
// Phase p: { MFMA(p) on regs[p&1]  ||  S1 ds_reads(p+1) -> regs[(p+1)&1] }
//          lgkm(0) ; W-round + A-glds(p+3 -> Abuf[p%3]) ; vmwait<4|5|6> ; bar.
// ---------------------------------------------------------------------------
__global__ __launch_bounds__(256, 2) void conv11_kernel(
    const unsigned short* __restrict__ Wp, const unsigned short* __restrict__ xT,
    const float* __restrict__ gamma, const float* __restrict__ beta,
    const float* __restrict__ mean, const float* __restrict__ var,
    float* __restrict__ out) {
  __shared__ __align__(16) unsigned short Abuf[3][8192];  // 3 x 16 KiB (2 steps each)
  __shared__ __align__(16) unsigned short Wbuf[2][5120];  // 2 x 10 KiB (2 rows)
  __shared__ float s_scale[128], s_shift[128];

  const int tid = threadIdx.x;
  const int bid = blockIdx.x;
  const int b = bid & 7;  // XCD-aware: blocks on XCD k share batch image k
  const int h0 = ((bid >> 3) & 31) * 2;
  const int c2t = bid >> 8;

  const int wid = tid >> 6, lane = tid & 63;
  const int wr = wid >> 1, wc = wid & 1;
  const int l31 = lane & 31, hi2 = lane >> 5;

  if (tid < 128) {
    const int c2 = c2t * 128 + tid;
    const float inv = gamma[c2] * rsqrtf(var[c2] + EPS);
    s_scale[tid] = inv;
    s_shift[tid] = beta[c2] - mean[c2] * inv;
  }

  int aoffs[2][2];
#pragma unroll
  for (int mt = 0; mt < 2; ++mt)
#pragma unroll
    for (int ks = 0; ks < 2; ++ks) {
      const int m = wr * 64 + mt * 32 + l31;
      aoffs[mt][ks] = m * 64 + (((ks * 2 + hi2) ^ swz4(m)) << 4);
    }
  int ndh[2], nwl[2];
#pragma unroll
  for (int nt = 0; nt < 2; ++nt) {
    const int n = wc * 64 + nt * 32 + l31;
    ndh[nt] = n >> 6;
    nwl[nt] = n & 63;
  }

  const int tid8 = tid * 8, tid2 = tid * 2;
  const int widA = wid * 512, wid128 = wid * 128;

  const size_t c2base = (size_t)c2t * 1352;
  const int bc8 = b * 8;
  const char* Abase = (const char*)&Abuf[0][0];
  unsigned short* AbaseU = &Abuf[0][0];

  auto wtile = [&](int T) -> const unsigned short* {
    const int kh = T >> 3, c1c = T & 7;
    return xT + (size_t)((bc8 + c1c) * 76 + h0 + kh) * 2560;
  };

  f32x16 acc[2][2];
#pragma unroll
  for (int i = 0; i < 2; ++i)
#pragma unroll
    for (int j = 0; j < 2; ++j)
#pragma unroll
      for (int r = 0; r < 16; ++r) acc[i][j][r] = 0.f;

  // double-buffered fragment registers: rE (even phases), rO (odd phases)
  bf16x8 rE_A[2][2][2], rE_B[2][2][2], rO_A[2][2][2], rO_B[2][2][2];

  // rotating byte offsets of the 3 A buffers: at phase p,
  // aCur = p%3 (glds target, data for p+3), aNext = (p+1)%3 (S1 reads now)
  int aCur = 0, aNext = 16384, aNN = 32768;

  // ---- prologue: A phases 0,1,2 (steps 0..5) -> bufs 0,1,2; W tile0 -> Wbuf0
  {
    const unsigned short* ws = wtile(0);
    glds16(ws + tid8, &Wbuf[0][0] + widA);
    glds16(ws + 2048 + tid8, &Wbuf[0][2048] + widA);
    glds4(ws + 4096 + tid2, &Wbuf[0][4096] + wid128);
    glds4(ws + 4608 + tid2, &Wbuf[0][4608] + wid128);
#pragma unroll
    for (int ph = 0; ph < 3; ++ph) {
      const unsigned short* at0 = Wp + ((c2base + 2 * ph) << 12);
      const unsigned short* at1 = Wp + ((c2base + 2 * ph + 1) << 12);
      unsigned short* ad = AbaseU + ph * 8192;
      glds16(at0 + tid8, ad + widA);
      glds16(at0 + 2048 + tid8, ad + 2048 + widA);
      glds16(at1 + tid8, ad + 4096 + widA);
      glds16(at1 + 2048 + tid8, ad + 6144 + widA);
    }
    vmwait<0>();
    __builtin_amdgcn_s_barrier();
    // preload regs for phase 0 (KWA=0,WBA=0,KWB=1,WBB=0) from Abuf[0]
    const char* abA = Abase;
    const char* abB = Abase + 8192;
    const char* wb0 = (const char*)&Wbuf[0][0];
#pragma unroll
    for (int ks = 0; ks < 2; ++ks) {
      rE_A[0][ks][0] = *(const bf16x8*)(abA + aoffs[0][ks]);
      rE_A[0][ks][1] = *(const bf16x8*)(abA + aoffs[1][ks]);
      rE_A[1][ks][0] = *(const bf16x8*)(abB + aoffs[0][ks]);
      rE_A[1][ks][1] = *(const bf16x8*)(abB + aoffs[1][ks]);
#pragma unroll
      for (int nt = 0; nt < 2; ++nt) {
        const int cA = nwl[nt] + 0 + 2;
        rE_B[0][ks][nt] = *(const bf16x8*)(wb0 + (ndh[nt] * 80 + cA) * 64 +
                                           (((ks * 2 + hi2) ^ swz4(cA)) << 4));
        const int cB = nwl[nt] + 1 + 2;
        rE_B[1][ks][nt] = *(const bf16x8*)(wb0 + (ndh[nt] * 80 + cB) * 64 +
                                           (((ks * 2 + hi2) ^ swz4(cB)) << 4));
      }
    }
    asm volatile("s_waitcnt lgkmcnt(0)" ::: "memory");
    __builtin_amdgcn_s_barrier();
    __builtin_amdgcn_sched_barrier(0);
  }

// Phase macro. RC*/current regs (MFMA), RN*/next regs (S1 reads, params N*).
#define PHASE(PH, RCA, RCB, RNA, RNB, NKWA, NWBA, NKWB, NWBB, WRT, WSRCP, WDB)\
  {                                                                           \
    __builtin_amdgcn_s_setprio(1);                                            \
    /* S1 reads for phase PH+1 (buffers ready since bar(PH-1)) */             \
    {                                                                         \
      const char* abA = Abase + aNext;                                        \
      const char* abB = abA + 8192;                                           \
      const char* wbA = (const char*)&Wbuf[(NWBA)][0];                        \
      const char* wbB = (const char*)&Wbuf[(NWBB)][0];                        \
      _Pragma("unroll") for (int ks = 0; ks < 2; ++ks) {                      \
        RNA[0][ks][0] = *(const bf16x8*)(abA + aoffs[0][ks]);                 \
        RNA[0][ks][1] = *(const bf16x8*)(abA + aoffs[1][ks]);                 \
        RNA[1][ks][0] = *(const bf16x8*)(abB + aoffs[0][ks]);                 \
        RNA[1][ks][1] = *(const bf16x8*)(abB + aoffs[1][ks]);                 \
        _Pragma("unroll") for (int nt = 0; nt < 2; ++nt) {                    \
          const int cA = nwl[nt] + (NKWA) + 2;                                \
          RNB[0][ks][nt] = *(const bf16x8*)(                                  \
              wbA + (ndh[nt] * 80 + cA) * 64 +                                \
              (((ks * 2 + hi2) ^ swz4(cA)) << 4));                            \
          const int cB = nwl[nt] + (NKWB) + 2;                                \
          RNB[1][ks][nt] = *(const bf16x8*)(                                  \
              wbB + (ndh[nt] * 80 + cB) * 64 +                                \
              (((ks * 2 + hi2) ^ swz4(cB)) << 4));                            \
        }                                                                     \
      }                                                                       \
    }                                                                         \
    /* MFMA(PH) on current regs — interleaves with the reads above */         \
    _Pragma("unroll") for (int s = 0; s < 2; ++s)                             \
        _Pragma("unroll") for (int ks = 0; ks < 2; ++ks) {                    \
      acc[0][0] = __builtin_amdgcn_mfma_f32_32x32x16_bf16(                    \
          RCA[s][ks][0], RCB[s][ks][0], acc[0][0], 0, 0, 0);                  \
      acc[0][1] = __builtin_amdgcn_mfma_f32_32x32x16_bf16(                    \
          RCA[s][ks][0], RCB[s][ks][1], acc[0][1], 0, 0, 0);                  \
      acc[1][0] = __builtin_amdgcn_mfma_f32_32x32x16_bf16(                    \
          RCA[s][ks][1], RCB[s][ks][0], acc[1][0], 0, 0, 0);                  \
      acc[1][1] = __builtin_amdgcn_mfma_f32_32x32x16_bf16(                    \
          RCA[s][ks][1], RCB[s][ks][1], acc[1][1], 0, 0, 0);                  \
    }                                                                         \
    __builtin_amdgcn_s_setprio(0);                                            \
    asm volatile("s_waitcnt lgkmcnt(0)" ::: "memory"); /* S1 done pre-bar */  \
    /* W round for a future tile */                                           \
    if ((WRT) == 1) glds16((WSRCP) + tid8, &Wbuf[(WDB)][0] + widA);           \
    if ((WRT) == 2)                                                           \
      glds16((WSRCP) + 2048 + tid8, &Wbuf[(WDB)][2048] + widA);               \
    if ((WRT) == 3) {                                                         \
      glds4((WSRCP) + 4096 + tid2, &Wbuf[(WDB)][4096] + wid128);              \
      glds4((WSRCP) + 4608 + tid2, &Wbuf[(WDB)][4608] + wid128);              \
    }                                                                         \
    /* A glds for phase PH+3 into Abuf[PH%3] (its data now lives in regs) */  \
    {                                                                         \
      int sn0 = S0 + 2 * (PH) + 6;                                            \
      if (sn0 >= 1352) sn0 -= 1352;                                           \
      int sn1 = sn0 + 1;                                                      \
      if (sn1 >= 1352) sn1 -= 1352;                                           \
      const unsigned short* at0 = Wp + ((c2base + (size_t)sn0) << 12);        \
      const unsigned short* at1 = Wp + ((c2base + (size_t)sn1) << 12);        \
      unsigned short* ad = AbaseU + (aCur >> 1);                              \
      glds16(at0 + tid8, ad + widA);                                          \
      glds16(at0 + 2048 + tid8, ad + 2048 + widA);                            \
      glds16(at1 + tid8, ad + 4096 + widA);                                   \
      glds16(at1 + 2048 + tid8, ad + 6144 + widA);                            \
    }                                                                         \
    vmwait<((WRT) == 0 ? 4 : ((WRT) == 3 ? 6 : 5))>();                        \
    __builtin_amdgcn_s_barrier();                                             \
    __builtin_amdgcn_sched_barrier(0);                                        \
    { const int t_ = aCur; aCur = aNext; aNext = aNN; aNN = t_; }             \
  }

  // 26 u-iterations x 26 phases. N-params = consume params of phase PH+1.
  // W rounds shifted -2 vs conv10 (fill->first-read gap >= 2 phases).
  for (int u = 0; u < 26; ++u) {
    const int S0 = u * 52;
    const int Tb = u * 4;
    const unsigned short* wt1 = wtile(Tb + 1);
    const unsigned short* wt2 = wtile(Tb + 2);
    const unsigned short* wt3 = wtile(Tb + 3);
    const unsigned short* wt4 = wtile((Tb + 4 == 104) ? 0 : Tb + 4);
    PHASE(0, rE_A, rE_B, rO_A, rO_B, 2, 0, 3, 0, 0, wt1, 1)
    PHASE(1, rO_A, rO_B, rE_A, rE_B, 4, 0, 5, 0, 1, wt1, 1)
    PHASE(2, rE_A, rE_B, rO_A, rO_B, 6, 0, 7, 0, 2, wt1, 1)
    PHASE(3, rO_A, rO_B, rE_A, rE_B, 8, 0, 9, 0, 3, wt1, 1)
    PHASE(4, rE_A, rE_B, rO_A, rO_B, 10, 0, 11, 0, 0, wt1, 1)
    PHASE(5, rO_A, rO_B, rE_A, rE_B, 12, 0, 0, 1, 0, wt1, 1)
    PHASE(6, rE_A, rE_B, rO_A, rO_B, 1, 1, 2, 1, 0, wt1, 1)
    PHASE(7, rO_A, rO_B, rE_A, rE_B, 3, 1, 4, 1, 1, wt2, 0)
    PHASE(8, rE_A, rE_B, rO_A, rO_B, 5, 1, 6, 1, 2, wt2, 0)
    PHASE(9, rO_A, rO_B, rE_A, rE_B, 7, 1, 8, 1, 3, wt2, 0)
    PHASE(10, rE_A, rE_B, rO_A, rO_B, 9, 1, 10, 1, 0, wt2, 0)
    PHASE(11, rO_A, rO_B, rE_A, rE_B, 11, 1, 12, 1, 0, wt2, 0)
    PHASE(12, rE_A, rE_B, rO_A, rO_B, 0, 0, 1, 0, 0, wt2, 0)
    PHASE(13, rO_A, rO_B, rE_A, rE_B, 2, 0, 3, 0, 0, wt3, 1)
    PHASE(14, rE_A, rE_B, rO_A, rO_B, 4, 0, 5, 0, 1, wt3, 1)
    PHASE(15, rO_A, rO_B, rE_A, rE_B, 6, 0, 7, 0, 2, wt3, 1)
    PHASE(16, rE_A, rE_B, rO_A, rO_B, 8, 0, 9, 0, 3, wt3, 1)
    PHASE(17, rO_A, rO_B, rE_A, rE_B, 10, 0, 11, 0, 0, wt3, 1)
    PHASE(18, rE_A, rE_B, rO_A, rO_B, 12, 0, 0, 1, 0, wt3, 1)
    PHASE(19, rO_A, rO_B, rE_A, rE_B, 1, 1, 2, 1, 0, wt3, 1)
    PHASE(20, rE_A, rE_B, rO_A, rO_B, 3, 1, 4, 1, 1, wt4, 0)
    PHASE(21, rO_A, rO_B, rE_A, rE_B, 5, 1, 6, 1, 2, wt4, 0)
    PHASE(22, rE_A, rE_B, rO_A, rO_B, 7, 1, 8, 1, 3, wt4, 0)
    PHASE(23, rO_A, rO_B, rE_A, rE_B, 9, 1, 10, 1, 0, wt4, 0)
    PHASE(24, rE_A, rE_B, rO_A, rO_B, 11, 1, 12, 1, 0, wt4, 0)
    PHASE(25, rO_A, rO_B, rE_A, rE_B, 0, 0, 1, 0, 0, wt4, 0)
  }
#undef PHASE

  vmwait<0>();  // drain dangling prefetches

  // ---- epilogue: BN + SiLU.
  // 32x32 C/D layout (m74/m101): col = lane&31, row = (r&3)+8*(r>>2)+4*(lane>>5)
#pragma unroll
  for (int mt = 0; mt < 2; ++mt) {
#pragma unroll
    for (int nt = 0; nt < 2; ++nt) {
      const int n = wc * 64 + nt * 32 + l31;
      const int hh = h0 + (n >> 6), ww = n & 63;
#pragma unroll
      for (int r = 0; r < 16; ++r) {
        const int mloc = (r & 3) + 8 * (r >> 2) + 4 * hi2;
        const int c2l = wr * 64 + mt * 32 + mloc;
        const float y = acc[mt][nt][r] * s_scale[c2l] + s_shift[c2l];
        out[((size_t)(b * 256 + c2t * 128 + c2l)) * 4096 + hh * 64 + ww] =
            y / (1.f + __expf(-y));
      }
    }
  }
}

// ---------------------------------------------------------------------------
// Safety-net fallback if workspace is too small for packed buffers.
// ---------------------------------------------------------------------------
__global__ void naive_conv_kernel(
    const float* __restrict__ x, const float* __restrict__ W,
    const float* __restrict__ gamma, const float* __restrict__ beta,
    const float* __restrict__ mean, const float* __restrict__ var,
    float* __restrict__ out) {
  const int idx = blockIdx.x * 256 + threadIdx.x;
  if (idx >= 8 * 256 * 64 * 64) return;
  const int w = idx & 63, h = (idx >> 6) & 63;
  const int c2 = (idx >> 12) & 255, b = idx >> 20;
  float s = 0.f;
  for (int c1 = 0; c1 < 256; ++c1) {
    const float* xp = x + ((size_t)(b * 256 + c1) * 4096);
    const float* wp = W + ((size_t)(c2 * 256 + c1) * 169);
    for (int kh = 0; kh < 13; ++kh) {
      const int r = h + kh - 6;
      if ((unsigned)r >= 64u) continue;
      for (int kw = 0; kw < 13; ++kw) {
        const int c = w + kw - 6;
        if ((unsigned)c >= 64u) continue;
        s += xp[r * 64 + c] * wp[kh * 13 + kw];
      }
    }
  }
  const float inv = gamma[c2] * rsqrtf(var[c2] + EPS);
  const float y = s * inv + (beta[c2] - mean[c2] * inv);
  out[idx] = y / (1.f + __expf(-y));
}

extern "C" void kernel_launch(void* const* d_in, const int* in_sizes, int n_in,
                              void* d_out, int out_size, void* d_ws, size_t ws_size,
                              hipStream_t stream) {
  const float* x = (const float*)d_in[0];
  const float* W = (const float*)d_in[1];
  const float* gamma = (const float*)d_in[2];
  const float* beta = (const float*)d_in[3];
  const float* mean = (const float*)d_in[4];
  const float* var = (const float*)d_in[5];
  float* out = (float*)d_out;

  const size_t WP_BYTES = (size_t)256 * 43264 * 2;  // 22,151,168
  const size_t XT_BYTES = (size_t)12455424 * 2;     // 24,910,848

  if (ws_size >= WP_BYTES + XT_BYTES) {
    unsigned short* Wp = (unsigned short*)d_ws;
    unsigned short* xT = (unsigned short*)((char*)d_ws + WP_BYTES);
    pack_w_kernel<<<256 * 13, 256, 0, stream>>>(W, Wp);
    pack_xt_kernel<<<8 * 8 * 76, 256, 0, stream>>>(x, xT);
    conv11_kernel<<<512, 256, 0, stream>>>(Wp, xT, gamma, beta, mean, var, out);
  } else {
    naive_conv_kernel<<<(8 * 256 * 64 * 64 + 255) / 256, 256, 0, stream>>>(
        x, W, gamma, beta, mean, var, out);
  }
}